// Round 2
// baseline (3150.107 us; speedup 1.0000x reference)
//
#include <hip/hip_runtime.h>
#include <hip/hip_fp16.h>

// BilinearAttention: context = softmax(mask? -1e9 : Q@K) @ V
// B=16, Tq=Tk=2048, D=1024, fp32 in/out.
// Round 3: pipelined MFMA flash attention.
//   QK^T : fp16 2-term split S=(Qh+Ql)*Kh (2x mfma_f32_16x16x32_f16);
//          K rounding error on scores ~0.0045 std (negligible after softmax).
//   P@V  : fp16 (P in [0,1]; V fp16), fp32 MFMA accum.
//   Pipelining: Q LDS double-buffered (1 barrier/c), Q/K/V global loads
//   issued 1-2 phases ahead into registers (T14 issue-early/write-late),
//   next-tile Q/K issued during last PV chunk.

#define B_    16
#define TQ    2048
#define TK    2048
#define DH    1024
#define BQ    64
#define BT    256
#define DC    128
#define NTHR  512
#define NEG_INF_ -1.0e9f

typedef __attribute__((ext_vector_type(8))) _Float16  f16x8;
typedef __attribute__((ext_vector_type(4))) _Float16  f16x4;
typedef __attribute__((ext_vector_type(4))) float     f32x4;

// ---------------- mask dtype detection (verified) ------------------------
// flag: 0 = int32, 1 = float32, 2 = uint8 bytes.
__global__ void detect_mask_kernel(const void* __restrict__ mask, int* flag_out) {
    const int tid = threadIdx.x;
    const int*   mi = (const int*)mask;
    const float* mf = (const float*)mask;
    int ok_i = 1, ok_f = 1;
    for (int k = 0; k < 16; ++k) {
        int idx = tid * 16 + k;
        int iv = mi[idx];
        ok_i &= ((iv == 0) | (iv == 1));
        float fv = mf[idx];
        ok_f &= ((fv == 0.0f) | (fv == 1.0f));
    }
    int all_i = __syncthreads_and(ok_i);
    int all_f = __syncthreads_and(ok_f);
    if (tid == 0) flag_out[0] = all_i ? 0 : (all_f ? 1 : 2);
}

// ---------------- DPP 16-lane row reduce (VALU-rate, no DS) --------------
template<int CTRL>
__device__ __forceinline__ float dpp_rot(float x) {
    return __int_as_float(__builtin_amdgcn_update_dpp(
        0, __float_as_int(x), CTRL, 0xf, 0xf, false));
}
__device__ __forceinline__ float rowmax16(float v) {
    v = fmaxf(v, dpp_rot<0x128>(v));   // row_ror:8
    v = fmaxf(v, dpp_rot<0x124>(v));   // row_ror:4
    v = fmaxf(v, dpp_rot<0x122>(v));   // row_ror:2
    v = fmaxf(v, dpp_rot<0x121>(v));   // row_ror:1
    return v;
}
__device__ __forceinline__ float rowsum16(float v) {
    v += dpp_rot<0x128>(v);
    v += dpp_rot<0x124>(v);
    v += dpp_rot<0x122>(v);
    v += dpp_rot<0x121>(v);
    return v;
}

// issue K loads: rows [D0+g*8,+8) at cols TCOL, TCOL+16 -> raw f32[8] x2
#define LOADK_(TCOL, D0, R0, R1) do {                                       \
    const float* kp_ = Kb + (size_t)((D0) + g * 8) * TK + (TCOL);           \
    _Pragma("unroll")                                                       \
    for (int j_ = 0; j_ < 8; ++j_) {                                        \
        (R0)[j_] = kp_[(size_t)j_ * TK];                                    \
        (R1)[j_] = kp_[(size_t)j_ * TK + 16];                               \
    }                                                                       \
} while (0)

#define KCVT_(SRC, DST) do {                                                \
    _Pragma("unroll")                                                       \
    for (int j_ = 0; j_ < 8; ++j_) (DST)[j_] = (_Float16)(SRC)[j_];         \
} while (0)

// issue Q loads for d-chunk DC_ -> qreg (4 x float4 per thread)
#define QLOAD_(DC_) do {                                                    \
    const float* qrow_ = Qb + (size_t)(tid >> 3) * DH + (DC_) + (tid & 7) * 16; \
    qreg[0] = *(const float4*)(qrow_ + 0);                                  \
    qreg[1] = *(const float4*)(qrow_ + 4);                                  \
    qreg[2] = *(const float4*)(qrow_ + 8);                                  \
    qreg[3] = *(const float4*)(qrow_ + 12);                                 \
} while (0)

// cvt qreg -> fp16 hi/lo, write to LDS buf CB (XOR-swizzled rows)
#define QSTORE_(CB) do {                                                    \
    const int qq_   = tid >> 3;                                             \
    const int sw_   = (qq_ & 7) << 4;                                       \
    const int rowb_ = qq_ * (DC * 2);                                       \
    _Pragma("unroll")                                                       \
    for (int i_ = 0; i_ < 4; ++i_) {                                        \
        const int d_ = (tid & 7) * 16 + i_ * 4;                             \
        const float* qf_ = reinterpret_cast<const float*>(&qreg[i_]);       \
        f16x4 h4_, l4_;                                                     \
        _Pragma("unroll")                                                   \
        for (int e_ = 0; e_ < 4; ++e_) {                                    \
            const _Float16 h_ = (_Float16)qf_[e_];                          \
            h4_[e_] = h_;                                                   \
            l4_[e_] = (_Float16)(qf_[e_] - (float)h_);                      \
        }                                                                   \
        const int off_ = rowb_ + ((d_ * 2) ^ sw_);                          \
        *(f16x4*)((char*)smu.qk.qh[CB] + off_) = h4_;                       \
        *(f16x4*)((char*)smu.qk.ql[CB] + off_) = l4_;                       \
    }                                                                       \
} while (0)

// issue V loads for 32-t chunk TC_ of tile T0_ -> vr (16 x float4)
#define VLOAD_(T0_, TC_) do {                                               \
    const int tb4_ = (tid & 7) * 4;                                         \
    const float* Vc_ = Vb + (size_t)((T0_) + (TC_) * 32 + tb4_) * DH;       \
    _Pragma("unroll")                                                       \
    for (int it_ = 0; it_ < 4; ++it_) {                                     \
        const int d4_ = (tid >> 3) * 4 + it_ * 256;                         \
        vr[it_][0] = *(const float4*)(Vc_ + 0 * DH + d4_);                  \
        vr[it_][1] = *(const float4*)(Vc_ + 1 * DH + d4_);                  \
        vr[it_][2] = *(const float4*)(Vc_ + 2 * DH + d4_);                  \
        vr[it_][3] = *(const float4*)(Vc_ + 3 * DH + d4_);                  \
    }                                                                       \
} while (0)

// cvt vr -> fp16, write transposed V^T[d][tloc] (80 B rows) to LDS
#define VSTORE_() do {                                                      \
    const int tb4_ = (tid & 7) * 4;                                         \
    _Pragma("unroll")                                                       \
    for (int it_ = 0; it_ < 4; ++it_) {                                     \
        const int d4_ = (tid >> 3) * 4 + it_ * 256;                         \
        const float* f0_ = reinterpret_cast<const float*>(&vr[it_][0]);     \
        const float* f1_ = reinterpret_cast<const float*>(&vr[it_][1]);     \
        const float* f2_ = reinterpret_cast<const float*>(&vr[it_][2]);     \
        const float* f3_ = reinterpret_cast<const float*>(&vr[it_][3]);     \
        _Pragma("unroll")                                                   \
        for (int i_ = 0; i_ < 4; ++i_) {                                    \
            f16x4 hv_;                                                      \
            hv_[0] = (_Float16)f0_[i_];                                     \
            hv_[1] = (_Float16)f1_[i_];                                     \
            hv_[2] = (_Float16)f2_[i_];                                     \
            hv_[3] = (_Float16)f3_[i_];                                     \
            *(f16x4*)((char*)smu.vst + (size_t)(d4_ + i_) * 80 + tb4_ * 2) = hv_; \
        }                                                                   \
    }                                                                       \
} while (0)

__global__ __launch_bounds__(NTHR, 2)
void flash_attn_kernel(const float* __restrict__ Q, const float* __restrict__ K,
                       const float* __restrict__ V, const void* __restrict__ Mask,
                       const int* __restrict__ flagp, float* __restrict__ Out) {
    __shared__ union {
        struct { unsigned short qh[2][BQ * DC];       // 2 x 16 KB fp16-hi
                 unsigned short ql[2][BQ * DC]; } qk; // 2 x 16 KB fp16-lo
        unsigned short vst[DH * 40];                  // 80 KB V^T fp16, 80B rows
    } smu;
    __shared__ unsigned short pbuf[BQ * BT];          // 32 KB P fp16, swizzled
    __shared__ float red [BQ][9];
    __shared__ float red2[BQ][9];
    __shared__ float m_s[BQ], l_s[BQ], alpha_s[BQ];

    const int tid  = threadIdx.x;
    const int w    = tid >> 6;     // wave 0..7
    const int ln   = tid & 63;
    const int g    = ln >> 4;      // 0..3 k-group / C-row-group
    const int lx   = ln & 15;      // 0..15 A-row / B-col / C-col
    const int flag = flagp[0];

    // XCD-grouped remap (dispatch i -> XCD i%8): XCD x gets batches {2x,2x+1}
    const int lin = blockIdx.y * gridDim.x + blockIdx.x;
    const int nl  = (lin & 7) * 64 + (lin >> 3);
    const int b   = nl >> 5;
    const int q0  = (nl & 31) * BQ;

    const float* Qb = Q + ((size_t)b * TQ + q0) * DH;
    const float* Kb = K + (size_t)b * DH * TK;
    const float* Vb = V + (size_t)b * TK * DH;

    const f32x4 zero4 = {0.f, 0.f, 0.f, 0.f};
    f32x4 acc[4][8];               // O: rows mt*16+g*4+r, cols w*128+nt*16+lx
#pragma unroll
    for (int mt = 0; mt < 4; ++mt)
#pragma unroll
        for (int nt = 0; nt < 8; ++nt) acc[mt][nt] = zero4;

    // persistent register staging buffers
    float4 qreg[4];
    float  kr0[2][8], kr1[2][8];
    float4 vr[4][4];

    // prologue: Q chunk 0 + K ks0/ks1 of tile 0 in flight
    QLOAD_(0);
    LOADK_(w * 32 + lx,  0, kr0[0], kr1[0]);
    LOADK_(w * 32 + lx, 32, kr0[1], kr1[1]);

    if (tid < BQ) { m_s[tid] = -3.0e38f; l_s[tid] = 0.0f; }
    __syncthreads();

#pragma unroll 1
    for (int t0 = 0; t0 < TK; t0 += BT) {
        const int tcol = t0 + w * 32 + lx;
        f32x4 sacc[4][2];
#pragma unroll
        for (int mt = 0; mt < 4; ++mt) { sacc[mt][0] = zero4; sacc[mt][1] = zero4; }

        __syncthreads();   // vst readers of previous tile done before qh writes

        // ============ QK^T : S[64][256], wave w -> cols [w*32,+32) ========
#pragma unroll 1
        for (int c = 0; c < DH / DC; ++c) {
            const int dc = c * DC;
            const int cb = c & 1;
            QSTORE_(cb);                       // waits on qreg, cvt, ds_write
            if (c < 7) QLOAD_(dc + DC);        // next chunk in flight over MFMA
            __syncthreads();                   // publish buf[cb]
#pragma unroll
            for (int ks = 0; ks < 4; ++ks) {
                f16x8 kh0, kh1;
                KCVT_(kr0[ks & 1], kh0);
                KCVT_(kr1[ks & 1], kh1);
                {   // prefetch K distance-2 (covers L2/LLC latency)
                    const int nk = ks + 2;
                    const int nc = c + (nk >> 2);
                    if (nc < 8)
                        LOADK_(tcol, nc * DC + (nk & 3) * 32, kr0[ks & 1], kr1[ks & 1]);
                }
                const int kloc = (ks * 32 + g * 8) * 2;
#pragma unroll
                for (int mt = 0; mt < 4; ++mt) {
                    const int row = mt * 16 + lx;
                    const int off = row * (DC * 2) + (kloc ^ ((row & 7) << 4));
                    const f16x8 aqh = *(const f16x8*)((const char*)smu.qk.qh[cb] + off);
                    const f16x8 aql = *(const f16x8*)((const char*)smu.qk.ql[cb] + off);
                    sacc[mt][0] = __builtin_amdgcn_mfma_f32_16x16x32_f16(aqh, kh0, sacc[mt][0], 0, 0, 0);
                    sacc[mt][0] = __builtin_amdgcn_mfma_f32_16x16x32_f16(aql, kh0, sacc[mt][0], 0, 0, 0);
                    sacc[mt][1] = __builtin_amdgcn_mfma_f32_16x16x32_f16(aqh, kh1, sacc[mt][1], 0, 0, 0);
                    sacc[mt][1] = __builtin_amdgcn_mfma_f32_16x16x32_f16(aql, kh1, sacc[mt][1], 0, 0, 0);
                }
            }
        }

        VLOAD_(t0, 0);   // V chunk 0 in flight over softmax

        // ============ mask + online softmax (in-register) =================
        float rmx[4][4];
#pragma unroll
        for (int mt = 0; mt < 4; ++mt)
#pragma unroll
        for (int r = 0; r < 4; ++r) {
            const int row = mt * 16 + g * 4 + r;
            const size_t mrow = ((size_t)(b * TQ + q0 + row)) * TK + tcol;
            bool mk0, mk1;
            if (flag == 0) {
                const int* Mi = (const int*)Mask;
                mk0 = Mi[mrow] != 0;        mk1 = Mi[mrow + 16] != 0;
            } else if (flag == 1) {
                const float* Mf = (const float*)Mask;
                mk0 = Mf[mrow] != 0.0f;     mk1 = Mf[mrow + 16] != 0.0f;
            } else {
                const unsigned char* Mu = (const unsigned char*)Mask;
                mk0 = Mu[mrow] != 0;        mk1 = Mu[mrow + 16] != 0;
            }
            if (mk0) sacc[mt][0][r] = NEG_INF_;
            if (mk1) sacc[mt][1][r] = NEG_INF_;
            rmx[mt][r] = rowmax16(fmaxf(sacc[mt][0][r], sacc[mt][1][r]));
        }
        if (lx == 0) {
#pragma unroll
            for (int mt = 0; mt < 4; ++mt)
#pragma unroll
            for (int r = 0; r < 4; ++r)
                red[mt * 16 + g * 4 + r][w] = rmx[mt][r];
        }
        __syncthreads();
        if (tid < BQ) {
            float m8 = red[tid][0];
#pragma unroll
            for (int k = 1; k < 8; ++k) m8 = fmaxf(m8, red[tid][k]);
            const float mo = m_s[tid];
            const float mn = fmaxf(mo, m8);
            m_s[tid]     = mn;
            alpha_s[tid] = __expf(mo - mn);   // exp(-3e38-mn) -> 0 on first tile
        }
        __syncthreads();
        // P = exp(S - m) -> fp16 LDS (swizzled), per-row partial sums
#pragma unroll
        for (int mt = 0; mt < 4; ++mt)
#pragma unroll
        for (int r = 0; r < 4; ++r) {
            const int row = mt * 16 + g * 4 + r;
            const float mn = m_s[row];
            const float p0 = __expf(sacc[mt][0][r] - mn);
            const float p1 = __expf(sacc[mt][1][r] - mn);
            const int rb = row * (BT * 2);
            const int sw = (row & 7) << 4;
            *(_Float16*)((char*)pbuf + rb + (((w * 32 + lx) * 2) ^ sw))      = (_Float16)p0;
            *(_Float16*)((char*)pbuf + rb + (((w * 32 + 16 + lx) * 2) ^ sw)) = (_Float16)p1;
            const float rs = rowsum16(p0 + p1);
            if (lx == 0) red2[row][w] = rs;
        }
        __syncthreads();
        if (tid < BQ) {
            float s8 = red2[tid][0];
#pragma unroll
            for (int k = 1; k < 8; ++k) s8 += red2[tid][k];
            l_s[tid] = l_s[tid] * alpha_s[tid] + s8;
        }
        // ---- rescale O by alpha ----
#pragma unroll
        for (int mt = 0; mt < 4; ++mt)
#pragma unroll
        for (int r = 0; r < 4; ++r) {
            const float a = alpha_s[mt * 16 + g * 4 + r];
#pragma unroll
            for (int nt = 0; nt < 8; ++nt) acc[mt][nt][r] *= a;
        }

        // ============ P@V : wave w -> O cols [w*128,+128) =================
#pragma unroll 1
        for (int tc = 0; tc < BT / 32; ++tc) {
            __syncthreads();                   // vst readers of tc-1 done
            VSTORE_();                         // waits on vr, cvt, transposed write
            if (tc < 7) {
                VLOAD_(t0, tc + 1);            // next chunk in flight over MFMA
            } else if (t0 + BT < TK) {
                QLOAD_(0);                     // next tile's Q chunk 0
                LOADK_(t0 + BT + w * 32 + lx,  0, kr0[0], kr1[0]);
                LOADK_(t0 + BT + w * 32 + lx, 32, kr0[1], kr1[1]);
            }
            __syncthreads();                   // publish vst
            f16x8 ap[4];
#pragma unroll
            for (int mt = 0; mt < 4; ++mt) {
                const int row = mt * 16 + lx;
                const int off = row * (BT * 2) + (((tc * 32 + g * 8) * 2) ^ ((row & 7) << 4));
                ap[mt] = *(const f16x8*)((const char*)pbuf + off);
            }
#pragma unroll
            for (int nt = 0; nt < 8; ++nt) {
                const int vrow = w * 128 + nt * 16 + lx;
                const f16x8 bv = *(const f16x8*)((const char*)smu.vst + (size_t)vrow * 80 + g * 16);
#pragma unroll
                for (int mt = 0; mt < 4; ++mt)
                    acc[mt][nt] = __builtin_amdgcn_mfma_f32_16x16x32_f16(ap[mt], bv, acc[mt][nt], 0, 0, 0);
            }
        }
    }

    // ============ epilogue: O /= l, store ================================
    __syncthreads();
#pragma unroll
    for (int mt = 0; mt < 4; ++mt)
#pragma unroll
    for (int r = 0; r < 4; ++r) {
        const int row = mt * 16 + g * 4 + r;
        const float inv = 1.0f / l_s[row];
        float* orow = Out + ((size_t)(b * TQ + q0 + row)) * DH + w * 128 + lx;
#pragma unroll
        for (int nt = 0; nt < 8; ++nt)
            orow[nt * 16] = acc[mt][nt][r] * inv;
    }
}

extern "C" void kernel_launch(void* const* d_in, const int* in_sizes, int n_in,
                              void* d_out, int out_size, void* d_ws, size_t ws_size,
                              hipStream_t stream) {
    const float* q    = (const float*)d_in[0];
    const float* k    = (const float*)d_in[1];
    const float* v    = (const float*)d_in[2];
    const void*  mask = d_in[3];
    float* out = (float*)d_out;
    int* flag = (int*)d_ws;   // only 4 bytes of ws used

    hipLaunchKernelGGL(detect_mask_kernel, dim3(1), dim3(256), 0, stream, mask, flag);
    dim3 grid(TQ / BQ, B_);
    hipLaunchKernelGGL(flash_attn_kernel, grid, dim3(NTHR), 0, stream,
                       q, k, v, mask, flag, out);
}

// Round 3
// 1494.920 us; speedup vs baseline: 2.1072x; 2.1072x over previous
//
#include <hip/hip_runtime.h>
#include <hip/hip_fp16.h>

// BilinearAttention: context = softmax(mask? -1e9 : Q@K) @ V
// B=16, Tq=Tk=2048, D=1024, fp32 in/out.
// Round 4: prepack fp16 into workspace + async-staged MFMA flash attention.
//   prep_k: K[b][d][t]->Kpk[b][d/8][t][8] fp16 (B-frag-ready, dwordx4/frag)
//   prep_v: V[b][t][d]->Vpk[b][t/8][d][8] fp16 (transpose folded in; PV frags
//           read DIRECT from global -- no V LDS staging, no vr spill)
//   prep_q: Q->Qh/Ql fp16 2-term tiles in exact swizzled-LDS image ->
//           main kernel stages Q via global_load_lds (async DMA, 0 VGPR/VALU)
//   Main: 512 thr / 8 waves, BQ=64, BT=256. Raw s_barrier + explicit waitcnt
//   so K prefetch (4-slot static ring, distance 2) survives barriers.
//   Register budget (hard 256/wave): acc 128 + sacc 32 + kfrag 32 + vslot 32.

#define B_    16
#define TQ    2048
#define TK    2048
#define DH    1024
#define BQ    64
#define BT    256
#define DC    128
#define NTHR  512
#define NEG_INF_ -1.0e9f

typedef __attribute__((ext_vector_type(8))) _Float16  f16x8;
typedef __attribute__((ext_vector_type(4))) _Float16  f16x4;
typedef __attribute__((ext_vector_type(4))) float     f32x4;
typedef unsigned int   u32;
typedef unsigned short u16;

// ---------------- mask dtype detection (verified) ------------------------
__global__ void detect_mask_kernel(const void* __restrict__ mask, int* flag_out) {
    const int tid = threadIdx.x;
    const int*   mi = (const int*)mask;
    const float* mf = (const float*)mask;
    int ok_i = 1, ok_f = 1;
    for (int k = 0; k < 16; ++k) {
        int idx = tid * 16 + k;
        int iv = mi[idx];
        ok_i &= ((iv == 0) | (iv == 1));
        float fv = mf[idx];
        ok_f &= ((fv == 0.0f) | (fv == 1.0f));
    }
    int all_i = __syncthreads_and(ok_i);
    int all_f = __syncthreads_and(ok_f);
    if (tid == 0) flag_out[0] = all_i ? 0 : (all_f ? 1 : 2);
}

// ---------------- DPP 16-lane row reduce ---------------------------------
template<int CTRL>
__device__ __forceinline__ float dpp_rot(float x) {
    return __int_as_float(__builtin_amdgcn_update_dpp(
        0, __float_as_int(x), CTRL, 0xf, 0xf, false));
}
__device__ __forceinline__ float rowmax16(float v) {
    v = fmaxf(v, dpp_rot<0x128>(v));
    v = fmaxf(v, dpp_rot<0x124>(v));
    v = fmaxf(v, dpp_rot<0x122>(v));
    v = fmaxf(v, dpp_rot<0x121>(v));
    return v;
}
__device__ __forceinline__ float rowsum16(float v) {
    v += dpp_rot<0x128>(v);
    v += dpp_rot<0x124>(v);
    v += dpp_rot<0x122>(v);
    v += dpp_rot<0x121>(v);
    return v;
}

__device__ __forceinline__ void gl_lds16(const u16* g, u16* l) {
    __builtin_amdgcn_global_load_lds(
        (const __attribute__((address_space(1))) u32*)(const void*)g,
        (__attribute__((address_space(3))) u32*)(void*)l, 16, 0, 0);
}

// ---------------- prepack kernels ----------------------------------------
// Q -> Qh,Ql: per (b,qb,c) a 16KB tile = swizzled LDS image:
//   byte off = qi*256 + ((2*dl) ^ ((qi&7)<<4)),  dl = local d * 2 bytes
__global__ __launch_bounds__(256)
void prep_q(const float* __restrict__ Q, u16* __restrict__ Qh, u16* __restrict__ Ql) {
    const size_t NU = (size_t)B_ * TQ * (DH / 8);
    for (size_t u = (size_t)blockIdx.x * 256 + threadIdx.x; u < NU;
         u += (size_t)gridDim.x * 256) {
        const int    dk = (int)(u & 127);
        const size_t bq = u >> 7;                 // b*2048+q
        const int    q  = (int)(bq & 2047);
        const int    b  = (int)(bq >> 11);
        const float* src = Q + (bq << 10) + dk * 8;
        float x[8];
        *(float4*)&x[0] = *(const float4*)src;
        *(float4*)&x[4] = *(const float4*)(src + 4);
        f16x8 h, l;
#pragma unroll
        for (int j = 0; j < 8; ++j) {
            h[j] = (_Float16)x[j];
            l[j] = (_Float16)(x[j] - (float)h[j]);
        }
        const int qb = q >> 6, qi = q & 63, c = dk >> 4;
        const int dl = (dk & 15) * 8;
        const size_t tile = ((size_t)(b * 32 + qb) * 8 + c) * 8192;
        const int eoff = (qi * 256 + ((dl * 2) ^ ((qi & 7) << 4))) >> 1;
        *(f16x8*)(Qh + tile + eoff) = h;
        *(f16x8*)(Ql + tile + eoff) = l;
    }
}

// K[b][d][t] -> Kpk[b][ds=d>>3][t][j=d&7] fp16
__global__ __launch_bounds__(256)
void prep_k(const float* __restrict__ K, u16* __restrict__ Kpk) {
    const size_t NU = (size_t)B_ * (DH / 8) * (TK / 4);
    for (size_t u = (size_t)blockIdx.x * 256 + threadIdx.x; u < NU;
         u += (size_t)gridDim.x * 256) {
        const int    t4  = (int)(u & 511);
        const size_t rem = u >> 9;
        const int    ds  = (int)(rem & 127);
        const int    b   = (int)(rem >> 7);
        const float* src = K + ((size_t)b * DH + ds * 8) * TK + t4 * 4;
        float x[8][4];
#pragma unroll
        for (int j = 0; j < 8; ++j)
            *(float4*)x[j] = *(const float4*)(src + (size_t)j * TK);
        u16* dst = Kpk + (((size_t)b * 128 + ds) * TK + t4 * 4) * 8;
#pragma unroll
        for (int i = 0; i < 4; ++i) {
            f16x8 o;
#pragma unroll
            for (int j = 0; j < 8; ++j) o[j] = (_Float16)x[j][i];
            *(f16x8*)(dst + i * 8) = o;
        }
    }
}

// V[b][t][d] -> Vpk[b][ts=t>>3][d][j=t&7] fp16 (transpose folded)
__global__ __launch_bounds__(256)
void prep_v(const float* __restrict__ V, u16* __restrict__ Vpk) {
    const size_t NU = (size_t)B_ * (TK / 8) * (DH / 4);
    for (size_t u = (size_t)blockIdx.x * 256 + threadIdx.x; u < NU;
         u += (size_t)gridDim.x * 256) {
        const int    d4  = (int)(u & 255);
        const size_t rem = u >> 8;
        const int    ts  = (int)(rem & 255);
        const int    b   = (int)(rem >> 8);
        const float* src = V + ((size_t)b * TK + ts * 8) * DH + d4 * 4;
        float x[8][4];
#pragma unroll
        for (int j = 0; j < 8; ++j)
            *(float4*)x[j] = *(const float4*)(src + (size_t)j * DH);
        u16* dst = Vpk + (((size_t)b * 256 + ts) * DH + d4 * 4) * 8;
#pragma unroll
        for (int i = 0; i < 4; ++i) {
            f16x8 o;
#pragma unroll
            for (int j = 0; j < 8; ++j) o[j] = (_Float16)x[j][i];
            *(f16x8*)(dst + i * 8) = o;
        }
    }
}

// ---------------- main kernel --------------------------------------------
// K step s (0..31): frags at rows ds = s*4+g, cols TCOL, TCOL+16
#define KISSUE(S, SLOT, TCOL) do {                                          \
    const u16* kp_ = Kb + (((size_t)((S) * 4 + g) * TK) + (TCOL)) * 8;      \
    kfrag[SLOT][0] = *(const f16x8*)kp_;                                    \
    kfrag[SLOT][1] = *(const f16x8*)(kp_ + 128);                            \
} while (0)

// async Q stage: chunk C -> LDS dbuf CB (prepacked layout == LDS image)
#define QISSUE(C, CB) do {                                                  \
    const u16* gh_ = Qhb + (size_t)(C) * 8192 + w * 1024 + ln * 8;          \
    const u16* gl_ = Qlb + (size_t)(C) * 8192 + w * 1024 + ln * 8;          \
    gl_lds16(gh_,       &qhs[CB][w * 1024]);                                \
    gl_lds16(gh_ + 512, &qhs[CB][w * 1024 + 512]);                          \
    gl_lds16(gl_,       &qls[CB][w * 1024]);                                \
    gl_lds16(gl_ + 512, &qls[CB][w * 1024 + 512]);                          \
} while (0)

// inline-Q fallback (QMODE 0): reg-load fp32 chunk, cvt+swizzled ds_write
#define QLOAD0(C) do {                                                      \
    const float* qr_ = Qb + (size_t)(tid >> 3) * DH + (C) * DC + (tid & 7) * 16; \
    qreg[0] = *(const float4*)(qr_);      qreg[1] = *(const float4*)(qr_ + 4);   \
    qreg[2] = *(const float4*)(qr_ + 8);  qreg[3] = *(const float4*)(qr_ + 12);  \
} while (0)

#define QSTORE0(CB) do {                                                    \
    const int qq_ = tid >> 3, sw_ = (qq_ & 7) << 4, rowb_ = qq_ * 256;      \
    _Pragma("unroll")                                                       \
    for (int i_ = 0; i_ < 4; ++i_) {                                        \
        const int d_ = (tid & 7) * 16 + i_ * 4;                             \
        const float* qf_ = reinterpret_cast<const float*>(&qreg[i_]);       \
        f16x4 h4_, l4_;                                                     \
        _Pragma("unroll")                                                   \
        for (int e_ = 0; e_ < 4; ++e_) {                                    \
            const _Float16 h_ = (_Float16)qf_[e_];                          \
            h4_[e_] = h_;                                                   \
            l4_[e_] = (_Float16)(qf_[e_] - (float)h_);                      \
        }                                                                   \
        const int off_ = rowb_ + ((d_ * 2) ^ sw_);                          \
        *(f16x4*)((char*)qhs[CB] + off_) = h4_;                             \
        *(f16x4*)((char*)qls[CB] + off_) = l4_;                             \
    }                                                                       \
} while (0)

// V quad QD (0..15): tc=QD>>1, nt base=(QD&1)*4, direct global B-frags
#define VQUAD(QD, SLOT) do {                                                \
    const size_t ts_ = (size_t)((t0 >> 3) + ((QD) >> 1) * 4 + g);           \
    const u16* vp_ = Vb + (ts_ * DH + w * 128 + ((QD) & 1) * 64 + lx) * 8;  \
    vslot[SLOT][0] = *(const f16x8*)(vp_);                                  \
    vslot[SLOT][1] = *(const f16x8*)(vp_ + 128);                            \
    vslot[SLOT][2] = *(const f16x8*)(vp_ + 256);                            \
    vslot[SLOT][3] = *(const f16x8*)(vp_ + 384);                            \
} while (0)

template<int QMODE>
__global__ __launch_bounds__(NTHR, 2)
void flash_mfma(const float* __restrict__ Q, const u16* __restrict__ Qh,
                const u16* __restrict__ Ql, const u16* __restrict__ Kpk,
                const u16* __restrict__ Vpk, const void* __restrict__ Mask,
                const int* __restrict__ flagp, float* __restrict__ Out) {
    __shared__ u16 qhs[2][BQ * DC];     // 2 x 16 KB fp16-hi (swizzled image)
    __shared__ u16 qls[2][BQ * DC];     // 2 x 16 KB fp16-lo
    __shared__ u16 pbuf[BQ * BT];       // 32 KB P fp16 (swizzled)
    __shared__ float red [BQ][9];
    __shared__ float red2[BQ][9];
    __shared__ float m_s[BQ], l_s[BQ], alpha_s[BQ];

    const int tid  = threadIdx.x;
    const int w    = tid >> 6;
    const int ln   = tid & 63;
    const int g    = ln >> 4;
    const int lx   = ln & 15;
    const int flag = flagp[0];

    // XCD-grouped remap: XCD x gets batches {2x,2x+1}
    const int lin = blockIdx.y * gridDim.x + blockIdx.x;
    const int nl  = (lin & 7) * 64 + (lin >> 3);
    const int b   = nl >> 5;
    const int q0  = (nl & 31) * BQ;

    const float* Qb  = Q + ((size_t)b * TQ + q0) * DH;
    const u16*   Qhb = Qh + ((size_t)(b * 32 + (q0 >> 6)) * 8) * 8192;
    const u16*   Qlb = Ql + ((size_t)(b * 32 + (q0 >> 6)) * 8) * 8192;
    const u16*   Kb  = Kpk + (size_t)b * DH * TK;   // 128*TK*8 elems
    const u16*   Vb  = Vpk + (size_t)b * TK * DH;   // 256*DH*8 elems

    const f32x4 zero4 = {0.f, 0.f, 0.f, 0.f};
    f32x4 acc[4][8];
#pragma unroll
    for (int mt = 0; mt < 4; ++mt)
#pragma unroll
        for (int nt = 0; nt < 8; ++nt) acc[mt][nt] = zero4;

    f16x8  kfrag[4][2];     // K-step ring, static slot = step&3
    f16x8  vslot[2][4];     // V quad dbuf, static slot = quad parity
    float4 qreg[4];         // QMODE 0 only

    // prologue: Q chunk0 + K steps 0,1 of tile 0 in flight
    if (QMODE == 1) QISSUE(0, 0); else QLOAD0(0);
    KISSUE(0, 0, w * 32 + lx);
    KISSUE(1, 1, w * 32 + lx);

    if (tid < BQ) { m_s[tid] = -3.0e38f; l_s[tid] = 0.0f; }

#pragma unroll 1
    for (int t0 = 0; t0 < TK; t0 += BT) {
        const int tcol = t0 + w * 32 + lx;
        f32x4 sacc[4][2];
#pragma unroll
        for (int mt = 0; mt < 4; ++mt) { sacc[mt][0] = zero4; sacc[mt][1] = zero4; }

        // ============ QK^T : S[64][256], wave w -> cols [w*32,+32) ========
#pragma unroll 1
        for (int c = 0; c < 8; ++c) {
            const int cb = c & 1;
            if (QMODE == 0) {
                QSTORE0(cb);
                if (c < 7) QLOAD0(c + 1);
                asm volatile("s_waitcnt lgkmcnt(0)" ::: "memory");
            } else {
                asm volatile("s_waitcnt vmcnt(0)" ::: "memory");
            }
            __builtin_amdgcn_sched_barrier(0);
            __builtin_amdgcn_s_barrier();
            __builtin_amdgcn_sched_barrier(0);
            if (QMODE == 1 && c < 7) QISSUE(c + 1, cb ^ 1);
#pragma unroll
            for (int ks = 0; ks < 4; ++ks) {
                const int s2 = c * 4 + ks + 2;
                if (s2 < 32) KISSUE(s2, (ks + 2) & 3, tcol);
                const int kloc = (ks * 32 + g * 8) * 2;
                __builtin_amdgcn_s_setprio(1);
#pragma unroll
                for (int mt = 0; mt < 4; ++mt) {
                    const int row = mt * 16 + lx;
                    const int off = row * 256 + (kloc ^ ((row & 7) << 4));
                    const f16x8 aqh = *(const f16x8*)((const char*)qhs[cb] + off);
                    const f16x8 aql = *(const f16x8*)((const char*)qls[cb] + off);
                    sacc[mt][0] = __builtin_amdgcn_mfma_f32_16x16x32_f16(aqh, kfrag[ks & 3][0], sacc[mt][0], 0, 0, 0);
                    sacc[mt][0] = __builtin_amdgcn_mfma_f32_16x16x32_f16(aql, kfrag[ks & 3][0], sacc[mt][0], 0, 0, 0);
                    sacc[mt][1] = __builtin_amdgcn_mfma_f32_16x16x32_f16(aqh, kfrag[ks & 3][1], sacc[mt][1], 0, 0, 0);
                    sacc[mt][1] = __builtin_amdgcn_mfma_f32_16x16x32_f16(aql, kfrag[ks & 3][1], sacc[mt][1], 0, 0, 0);
                }
                __builtin_amdgcn_s_setprio(0);
            }
        }

        // ============ mask + online softmax (in-register) =================
        float rmx[4][4];
#pragma unroll
        for (int mt = 0; mt < 4; ++mt)
#pragma unroll
        for (int r = 0; r < 4; ++r) {
            const int row = mt * 16 + g * 4 + r;
            const size_t mrow = ((size_t)(b * TQ + q0 + row)) * TK + tcol;
            bool mk0, mk1;
            if (flag == 0) {
                const int* Mi = (const int*)Mask;
                mk0 = Mi[mrow] != 0;        mk1 = Mi[mrow + 16] != 0;
            } else if (flag == 1) {
                const float* Mf = (const float*)Mask;
                mk0 = Mf[mrow] != 0.0f;     mk1 = Mf[mrow + 16] != 0.0f;
            } else {
                const unsigned char* Mu = (const unsigned char*)Mask;
                mk0 = Mu[mrow] != 0;        mk1 = Mu[mrow + 16] != 0;
            }
            if (mk0) sacc[mt][0][r] = NEG_INF_;
            if (mk1) sacc[mt][1][r] = NEG_INF_;
            rmx[mt][r] = rowmax16(fmaxf(sacc[mt][0][r], sacc[mt][1][r]));
        }
        if (lx == 0) {
#pragma unroll
            for (int mt = 0; mt < 4; ++mt)
#pragma unroll
            for (int r = 0; r < 4; ++r)
                red[mt * 16 + g * 4 + r][w] = rmx[mt][r];
        }
        __syncthreads();
        if (tid < BQ) {
            float m8 = red[tid][0];
#pragma unroll
            for (int k = 1; k < 8; ++k) m8 = fmaxf(m8, red[tid][k]);
            const float mo = m_s[tid];
            const float mn = fmaxf(mo, m8);
            m_s[tid]     = mn;
            alpha_s[tid] = __expf(mo - mn);
        }
        __syncthreads();
#pragma unroll
        for (int mt = 0; mt < 4; ++mt)
#pragma unroll
        for (int r = 0; r < 4; ++r) {
            const int row = mt * 16 + g * 4 + r;
            const float mn = m_s[row];
            const float p0 = __expf(sacc[mt][0][r] - mn);
            const float p1 = __expf(sacc[mt][1][r] - mn);
            const int rb = row * (BT * 2);
            const int sw = (row & 7) << 4;
            *(_Float16*)((char*)pbuf + rb + (((w * 32 + lx) * 2) ^ sw))      = (_Float16)p0;
            *(_Float16*)((char*)pbuf + rb + (((w * 32 + 16 + lx) * 2) ^ sw)) = (_Float16)p1;
            const float rs = rowsum16(p0 + p1);
            if (lx == 0) red2[row][w] = rs;
        }
        __syncthreads();   // pbuf published; everyone past QK/qhs reads

        // next-tile prefetch (safe: all waves past qhs reads) + V quads 0,1
        if (t0 + BT < TK) {
            if (QMODE == 1) QISSUE(0, 0); else QLOAD0(0);
            KISSUE(0, 0, tcol + BT);
            KISSUE(1, 1, tcol + BT);
        }
        VQUAD(0, 0);
        VQUAD(1, 1);

        if (tid < BQ) {
            float s8 = red2[tid][0];
#pragma unroll
            for (int k = 1; k < 8; ++k) s8 += red2[tid][k];
            l_s[tid] = l_s[tid] * alpha_s[tid] + s8;
        }
        // ---- rescale O by alpha ----
#pragma unroll
        for (int mt = 0; mt < 4; ++mt)
#pragma unroll
        for (int r = 0; r < 4; ++r) {
            const float a = alpha_s[mt * 16 + g * 4 + r];
#pragma unroll
            for (int nt = 0; nt < 8; ++nt) acc[mt][nt][r] *= a;
        }

        // ============ P@V : direct-global V frags, no barriers ============
#pragma unroll 1
        for (int tc = 0; tc < 8; ++tc) {
            f16x8 ap[4];
#pragma unroll
            for (int mt = 0; mt < 4; ++mt) {
                const int row = mt * 16 + lx;
                const int off = row * (BT * 2) + (((tc * 32 + g * 8) * 2) ^ ((row & 7) << 4));
                ap[mt] = *(const f16x8*)((const char*)pbuf + off);
            }
#pragma unroll
            for (int h = 0; h < 2; ++h) {
                __builtin_amdgcn_s_setprio(1);
#pragma unroll
                for (int n = 0; n < 4; ++n) {
                    const int nt = h * 4 + n;
#pragma unroll
                    for (int mt = 0; mt < 4; ++mt)
                        acc[mt][nt] = __builtin_amdgcn_mfma_f32_16x16x32_f16(ap[mt], vslot[h][n], acc[mt][nt], 0, 0, 0);
                }
                __builtin_amdgcn_s_setprio(0);
                const int qd = tc * 2 + h + 2;
                if (qd < 16) {
                    if (h == 0) VQUAD(qd, 0); else VQUAD(qd, 1);
                }
            }
        }
    }

    // ============ epilogue: O /= l, store ================================
    __syncthreads();
#pragma unroll
    for (int mt = 0; mt < 4; ++mt)
#pragma unroll
    for (int r = 0; r < 4; ++r) {
        const int row = mt * 16 + g * 4 + r;
        const float inv = 1.0f / l_s[row];
        float* orow = Out + ((size_t)(b * TQ + q0 + row)) * DH + w * 128 + lx;
#pragma unroll
        for (int nt = 0; nt < 8; ++nt)
            orow[nt * 16] = acc[mt][nt][r] * inv;
    }
}

// ================= legacy fallback (round-2 kernel, verified) =============
#define LOADK_(TCOL, D0, R0, R1) do {                                       \
    const float* kp_ = Kb + (size_t)((D0) + g * 8) * TK + (TCOL);           \
    _Pragma("unroll")                                                       \
    for (int j_ = 0; j_ < 8; ++j_) {                                        \
        (R0)[j_] = kp_[(size_t)j_ * TK];                                    \
        (R1)[j_] = kp_[(size_t)j_ * TK + 16];                               \
    }                                                                       \
} while (0)
#define KCVT_(SRC, DST) do {                                                \
    _Pragma("unroll")                                                       \
    for (int j_ = 0; j_ < 8; ++j_) (DST)[j_] = (_Float16)(SRC)[j_];         \
} while (0)
#define LQLOAD_(DC_) do {                                                   \
    const float* qrow_ = Qb + (size_t)(tid >> 3) * DH + (DC_) + (tid & 7) * 16; \
    qreg[0] = *(const float4*)(qrow_ + 0);  qreg[1] = *(const float4*)(qrow_ + 4); \
    qreg[2] = *(const float4*)(qrow_ + 8);  qreg[3] = *(const float4*)(qrow_ + 12); \
} while (0)
#define LQSTORE_(CB) do {                                                   \
    const int qq_ = tid >> 3, sw_ = (qq_ & 7) << 4, rowb_ = qq_ * (DC * 2); \
    _Pragma("unroll")                                                       \
    for (int i_ = 0; i_ < 4; ++i_) {                                        \
        const int d_ = (tid & 7) * 16 + i_ * 4;                             \
        const float* qf_ = reinterpret_cast<const float*>(&qreg[i_]);       \
        f16x4 h4_, l4_;                                                     \
        _Pragma("unroll")                                                   \
        for (int e_ = 0; e_ < 4; ++e_) {                                    \
            const _Float16 h_ = (_Float16)qf_[e_];                          \
            h4_[e_] = h_;  l4_[e_] = (_Float16)(qf_[e_] - (float)h_);       \
        }                                                                   \
        const int off_ = rowb_ + ((d_ * 2) ^ sw_);                          \
        *(f16x4*)((char*)smu.qk.qh[CB] + off_) = h4_;                       \
        *(f16x4*)((char*)smu.qk.ql[CB] + off_) = l4_;                       \
    }                                                                       \
} while (0)
#define LVLOAD_(T0_, TC_) do {                                              \
    const int tb4_ = (tid & 7) * 4;                                         \
    const float* Vc_ = Vb + (size_t)((T0_) + (TC_) * 32 + tb4_) * DH;       \
    _Pragma("unroll")                                                       \
    for (int it_ = 0; it_ < 4; ++it_) {                                     \
        const int d4_ = (tid >> 3) * 4 + it_ * 256;                         \
        vr[it_][0] = *(const float4*)(Vc_ + 0 * DH + d4_);                  \
        vr[it_][1] = *(const float4*)(Vc_ + 1 * DH + d4_);                  \
        vr[it_][2] = *(const float4*)(Vc_ + 2 * DH + d4_);                  \
        vr[it_][3] = *(const float4*)(Vc_ + 3 * DH + d4_);                  \
    }                                                                       \
} while (0)
#define LVSTORE_() do {                                                     \
    const int tb4_ = (tid & 7) * 4;                                         \
    _Pragma("unroll")                                                       \
    for (int it_ = 0; it_ < 4; ++it_) {                                     \
        const int d4_ = (tid >> 3) * 4 + it_ * 256;                         \
        const float* f0_ = reinterpret_cast<const float*>(&vr[it_][0]);     \
        const float* f1_ = reinterpret_cast<const float*>(&vr[it_][1]);     \
        const float* f2_ = reinterpret_cast<const float*>(&vr[it_][2]);     \
        const float* f3_ = reinterpret_cast<const float*>(&vr[it_][3]);     \
        _Pragma("unroll")                                                   \
        for (int i_ = 0; i_ < 4; ++i_) {                                    \
            f16x4 hv_;                                                      \
            hv_[0] = (_Float16)f0_[i_];  hv_[1] = (_Float16)f1_[i_];        \
            hv_[2] = (_Float16)f2_[i_];  hv_[3] = (_Float16)f3_[i_];        \
            *(f16x4*)((char*)smu.vst + (size_t)(d4_ + i_) * 80 + tb4_ * 2) = hv_; \
        }                                                                   \
    }                                                                       \
} while (0)

__global__ __launch_bounds__(NTHR, 2)
void flash_attn_legacy(const float* __restrict__ Q, const float* __restrict__ K,
                       const float* __restrict__ V, const void* __restrict__ Mask,
                       const int* __restrict__ flagp, float* __restrict__ Out) {
    __shared__ union {
        struct { u16 qh[2][BQ * DC]; u16 ql[2][BQ * DC]; } qk;
        u16 vst[DH * 40];
    } smu;
    __shared__ u16 pbuf[BQ * BT];
    __shared__ float red[BQ][9], red2[BQ][9];
    __shared__ float m_s[BQ], l_s[BQ], alpha_s[BQ];

    const int tid = threadIdx.x, w = tid >> 6, ln = tid & 63;
    const int g = ln >> 4, lx = ln & 15, flag = flagp[0];
    const int lin = blockIdx.y * gridDim.x + blockIdx.x;
    const int nl = (lin & 7) * 64 + (lin >> 3);
    const int b = nl >> 5, q0 = (nl & 31) * BQ;
    const float* Qb = Q + ((size_t)b * TQ + q0) * DH;
    const float* Kb = K + (size_t)b * DH * TK;
    const float* Vb = V + (size_t)b * TK * DH;
    const f32x4 zero4 = {0.f, 0.f, 0.f, 0.f};
    f32x4 acc[4][8];
#pragma unroll
    for (int mt = 0; mt < 4; ++mt)
#pragma unroll
        for (int nt = 0; nt < 8; ++nt) acc[mt][nt] = zero4;
    float4 qreg[4];  float kr0[2][8], kr1[2][8];  float4 vr[4][4];
    LQLOAD_(0);
    LOADK_(w * 32 + lx, 0, kr0[0], kr1[0]);
    LOADK_(w * 32 + lx, 32, kr0[1], kr1[1]);
    if (tid < BQ) { m_s[tid] = -3.0e38f; l_s[tid] = 0.0f; }
    __syncthreads();
#pragma unroll 1
    for (int t0 = 0; t0 < TK; t0 += BT) {
        const int tcol = t0 + w * 32 + lx;
        f32x4 sacc[4][2];
#pragma unroll
        for (int mt = 0; mt < 4; ++mt) { sacc[mt][0] = zero4; sacc[mt][1] = zero4; }
        __syncthreads();
#pragma unroll 1
        for (int c = 0; c < DH / DC; ++c) {
            const int cb = c & 1;
            LQSTORE_(cb);
            if (c < 7) LQLOAD_(c * DC + DC);
            __syncthreads();
#pragma unroll
            for (int ks = 0; ks < 4; ++ks) {
                f16x8 kh0, kh1;
                KCVT_(kr0[ks & 1], kh0);  KCVT_(kr1[ks & 1], kh1);
                { const int nk = ks + 2, nc = c + (nk >> 2);
                  if (nc < 8) LOADK_(tcol, nc * DC + (nk & 3) * 32, kr0[ks & 1], kr1[ks & 1]); }
                const int kloc = (ks * 32 + g * 8) * 2;
#pragma unroll
                for (int mt = 0; mt < 4; ++mt) {
                    const int row = mt * 16 + lx;
                    const int off = row * (DC * 2) + (kloc ^ ((row & 7) << 4));
                    const f16x8 aqh = *(const f16x8*)((const char*)smu.qk.qh[cb] + off);
                    const f16x8 aql = *(const f16x8*)((const char*)smu.qk.ql[cb] + off);
                    sacc[mt][0] = __builtin_amdgcn_mfma_f32_16x16x32_f16(aqh, kh0, sacc[mt][0], 0, 0, 0);
                    sacc[mt][0] = __builtin_amdgcn_mfma_f32_16x16x32_f16(aql, kh0, sacc[mt][0], 0, 0, 0);
                    sacc[mt][1] = __builtin_amdgcn_mfma_f32_16x16x32_f16(aqh, kh1, sacc[mt][1], 0, 0, 0);
                    sacc[mt][1] = __builtin_amdgcn_mfma_f32_16x16x32_f16(aql, kh1, sacc[mt][1], 0, 0, 0);
                }
            }
        }
        LVLOAD_(t0, 0);
        float rmx[4][4];
#pragma unroll
        for (int mt = 0; mt < 4; ++mt)
#pragma unroll
        for (int r = 0; r < 4; ++r) {
            const int row = mt * 16 + g * 4 + r;
            const size_t mrow = ((size_t)(b * TQ + q0 + row)) * TK + tcol;
            bool mk0, mk1;
            if (flag == 0) { const int* Mi = (const int*)Mask; mk0 = Mi[mrow] != 0; mk1 = Mi[mrow + 16] != 0; }
            else if (flag == 1) { const float* Mf = (const float*)Mask; mk0 = Mf[mrow] != 0.0f; mk1 = Mf[mrow + 16] != 0.0f; }
            else { const unsigned char* Mu = (const unsigned char*)Mask; mk0 = Mu[mrow] != 0; mk1 = Mu[mrow + 16] != 0; }
            if (mk0) sacc[mt][0][r] = NEG_INF_;
            if (mk1) sacc[mt][1][r] = NEG_INF_;
            rmx[mt][r] = rowmax16(fmaxf(sacc[mt][0][r], sacc[mt][1][r]));
        }
        if (lx == 0) {
#pragma unroll
            for (int mt = 0; mt < 4; ++mt)
#pragma unroll
            for (int r = 0; r < 4; ++r) red[mt * 16 + g * 4 + r][w] = rmx[mt][r];
        }
        __syncthreads();
        if (tid < BQ) {
            float m8 = red[tid][0];
#pragma unroll
            for (int k = 1; k < 8; ++k) m8 = fmaxf(m8, red[tid][k]);
            const float mo = m_s[tid], mn = fmaxf(mo, m8);
            m_s[tid] = mn;  alpha_s[tid] = __expf(mo - mn);
        }
        __syncthreads();
#pragma unroll
        for (int mt = 0; mt < 4; ++mt)
#pragma unroll
        for (int r = 0; r < 4; ++r) {
            const int row = mt * 16 + g * 4 + r;
            const float mn = m_s[row];
            const float p0 = __expf(sacc[mt][0][r] - mn);
            const float p1 = __expf(sacc[mt][1][r] - mn);
            const int rb = row * (BT * 2), sw = (row & 7) << 4;
            *(_Float16*)((char*)pbuf + rb + (((w * 32 + lx) * 2) ^ sw)) = (_Float16)p0;
            *(_Float16*)((char*)pbuf + rb + (((w * 32 + 16 + lx) * 2) ^ sw)) = (_Float16)p1;
            const float rs = rowsum16(p0 + p1);
            if (lx == 0) red2[row][w] = rs;
        }
        __syncthreads();
        if (tid < BQ) {
            float s8 = red2[tid][0];
#pragma unroll
            for (int k = 1; k < 8; ++k) s8 += red2[tid][k];
            l_s[tid] = l_s[tid] * alpha_s[tid] + s8;
        }
#pragma unroll
        for (int mt = 0; mt < 4; ++mt)
#pragma unroll
        for (int r = 0; r < 4; ++r) {
            const float a = alpha_s[mt * 16 + g * 4 + r];
#pragma unroll
            for (int nt = 0; nt < 8; ++nt) acc[mt][nt][r] *= a;
        }
#pragma unroll 1
        for (int tc = 0; tc < BT / 32; ++tc) {
            __syncthreads();
            LVSTORE_();
            if (tc < 7) { LVLOAD_(t0, tc + 1); }
            else if (t0 + BT < TK) {
                LQLOAD_(0);
                LOADK_(t0 + BT + w * 32 + lx, 0, kr0[0], kr1[0]);
                LOADK_(t0 + BT + w * 32 + lx, 32, kr0[1], kr1[1]);
            }
            __syncthreads();
            f16x8 ap[4];
#pragma unroll
            for (int mt = 0; mt < 4; ++mt) {
                const int row = mt * 16 + lx;
                const int off = row * (BT * 2) + (((tc * 32 + g * 8) * 2) ^ ((row & 7) << 4));
                ap[mt] = *(const f16x8*)((const char*)pbuf + off);
            }
#pragma unroll
            for (int nt = 0; nt < 8; ++nt) {
                const int vrow = w * 128 + nt * 16 + lx;
                const f16x8 bv = *(const f16x8*)((const char*)smu.vst + (size_t)vrow * 80 + g * 16);
#pragma unroll
                for (int mt = 0; mt < 4; ++mt)
                    acc[mt][nt] = __builtin_amdgcn_mfma_f32_16x16x32_f16(ap[mt], bv, acc[mt][nt], 0, 0, 0);
            }
        }
    }
    __syncthreads();
#pragma unroll
    for (int mt = 0; mt < 4; ++mt)
#pragma unroll
    for (int r = 0; r < 4; ++r) {
        const int row = mt * 16 + g * 4 + r;
        const float inv = 1.0f / l_s[row];
        float* orow = Out + ((size_t)(b * TQ + q0 + row)) * DH + w * 128 + lx;
#pragma unroll
        for (int nt = 0; nt < 8; ++nt) orow[nt * 16] = acc[mt][nt][r] * inv;
    }
}

// ---------------- host ---------------------------------------------------
extern "C" void kernel_launch(void* const* d_in, const int* in_sizes, int n_in,
                              void* d_out, int out_size, void* d_ws, size_t ws_size,
                              hipStream_t stream) {
    const float* q    = (const float*)d_in[0];
    const float* k    = (const float*)d_in[1];
    const float* v    = (const float*)d_in[2];
    const void*  mask = d_in[3];
    float* out = (float*)d_out;
    int* flag = (int*)d_ws;

    hipLaunchKernelGGL(detect_mask_kernel, dim3(1), dim3(256), 0, stream, mask, flag);

    const size_t SZH = (size_t)B_ * TQ * DH * sizeof(u16);   // 64 MB
    char* wsb = (char*)d_ws + 1024;
    dim3 grid(TQ / BQ, B_);

    if (ws_size >= 4 * SZH + 1024) {
        u16* Kpk = (u16*)wsb;
        u16* Vpk = (u16*)(wsb + SZH);
        u16* Qh  = (u16*)(wsb + 2 * SZH);
        u16* Ql  = (u16*)(wsb + 3 * SZH);
        hipLaunchKernelGGL(prep_k, dim3(2048), dim3(256), 0, stream, k, Kpk);
        hipLaunchKernelGGL(prep_v, dim3(2048), dim3(256), 0, stream, v, Vpk);
        hipLaunchKernelGGL(prep_q, dim3(2048), dim3(256), 0, stream, q, Qh, Ql);
        hipLaunchKernelGGL(flash_mfma<1>, grid, dim3(NTHR), 0, stream,
                           q, Qh, Ql, Kpk, Vpk, mask, flag, out);
    } else if (ws_size >= 2 * SZH + 1024) {
        u16* Kpk = (u16*)wsb;
        u16* Vpk = (u16*)(wsb + SZH);
        hipLaunchKernelGGL(prep_k, dim3(2048), dim3(256), 0, stream, k, Kpk);
        hipLaunchKernelGGL(prep_v, dim3(2048), dim3(256), 0, stream, v, Vpk);
        hipLaunchKernelGGL(flash_mfma<0>, grid, dim3(NTHR), 0, stream,
                           q, (const u16*)nullptr, (const u16*)nullptr,
                           Kpk, Vpk, mask, flag, out);
    } else {
        hipLaunchKernelGGL(flash_attn_legacy, grid, dim3(NTHR), 0, stream,
                           q, k, v, mask, flag, out);
    }
}